// Round 12
// baseline (183.455 us; speedup 1.0000x reference)
//
#include <hip/hip_runtime.h>
#include <hip/hip_bf16.h>
#include <hip/hip_fp16.h>

#define N_NODES  100000
#define N_RADIAL 16
#define N_CONICAL 16

#define NPB    128                                   // nodes per bucket
#define NBKT   ((N_NODES + NPB - 1) / NPB)           // 782 buckets
#define NBLK_A 256                                   // binfuse scatter blocks
#define BTHR   1024                                  // binfuse block threads
#define SUBCAP 64                                    // per-(block,bucket) sub-run cap
                                                     // mean 16, sigma 4 -> +12σ, P(ovf)~1e-11 total
#define BKTSTRIDE (NBLK_A * SUBCAP)                  // 16384 slots per bucket (64KB, line-aligned)
#define CAP    5120                                  // bucket edges in LDS (mean 4096 + 16σ)

// ws byte offsets (256 MiB workspace; ~55 MB used)
#define XCON_OFF   0u
#define W1T_OFF    3200000u
#define W2T_OFF    3216384u
#define CNTS_OFF   3232768u
#define BINNED_OFF 4033536u

// ---------------------------------------------------------------------------
// A. Fused bin+prep (R11 structure, 1024-thread blocks for latency hiding:
//    R11 measured 46us at 8 waves/CU vs ~20us LDS-atomic floor -> double the
//    in-flight edges). Blocks 0..255: single-pass scatter into fixed-cap
//    per-(block,bucket) sub-runs, 1 LDS cursor atomic + 1 line-dense write
//    per edge; exact lengths to cnts. Block 256: weight transposes.
//    Blocks 257..: xcon f16 pack (3.2MB -> L2-resident, R6-verified).
// ---------------------------------------------------------------------------
__global__ __launch_bounds__(BTHR, 2) void binfuse_kernel(
    const int* __restrict__ idx, const float* __restrict__ x,
    __half2* __restrict__ xcon2,
    const float* __restrict__ W1, const float* __restrict__ W2,
    float* __restrict__ W1t, float* __restrict__ W2t,
    unsigned int* __restrict__ binned, int* __restrict__ cnts,
    int chunk, int total, int E) {
    int b = blockIdx.x, tid = threadIdx.x;
    if (b >= NBLK_A) {
        int pb = b - NBLK_A;
        if (pb == 0) {                       // weight transposes (4096 each)
            for (int i = tid; i < 4096; i += BTHR) {
                int c = i >> 7, k = i & 127;
                W1t[k * 32 + c] = W1[i];     // W1[c][k] -> W1t[k][c]
                int kk = i >> 5, o = i & 31;
                W2t[o * 128 + kk] = W2[i];   // W2[k][o] -> W2t[o][k]
            }
        } else {                             // xcon pack: one half2/thread
            int t = (pb - 1) * BTHR + tid;
            if (t < N_NODES * 8) {
                int n = t >> 3, p = t & 7;
                const float2* xp = (const float2*)x;
                float2 v = xp[n * 16 + 8 + p];
                xcon2[t] = __floats2half2_rn(v.x, v.y);
            }
        }
        return;
    }

    __shared__ int cur[NBKT];
    for (int i = tid; i < NBKT; i += BTHR)
        cur[i] = i * BKTSTRIDE + b * SUBCAP;       // absolute slot cursor
    __syncthreads();

    int lo = b * chunk;
    int hi = min(lo + chunk, total);
    for (int d = lo + tid; d < hi; d += BTHR) {
        int row = idx[d];
        int col = (d < E) ? idx[d + E] : idx[d - E];
        int bkt = row >> 7;
        int p = atomicAdd(&cur[bkt], 1);
        binned[p] = ((unsigned int)(row & 127) << 17) | (unsigned int)col;
    }
    __syncthreads();

    for (int i = tid; i < NBKT; i += BTHR)
        cnts[i * NBLK_A + b] = cur[i] - (i * BKTSTRIDE + b * SUBCAP);
}

// ---------------------------------------------------------------------------
// B. Fused agg+MLP: one block per 128-node bucket, 512 threads, 2 blocks/CU.
//    agg part (R7-verified): counting sort by local node (2 LDS atomics/
//    edge) into sedge, then atomic-free register accumulation (4 lanes/node
//    x 8B gathers from L2-resident xcon); result -> LDS aggL (no global
//    agg round-trip, no 3rd launch).
//    MLP part (R9-verified scheme, 2 tiles of 64 nodes): phase A computes
//    h-slices with wave-uniform W1t (scalar pipe), f16-packed into H2
//    (unioned with dead sedge); phase B computes 4 outs/wave from H2 + W2t.
// ---------------------------------------------------------------------------
__global__ __launch_bounds__(512, 4) void aggmlp_kernel(
    const __half* __restrict__ xcon, const int* __restrict__ cnts,
    const unsigned int* __restrict__ binned,
    const float* __restrict__ x,
    const float* __restrict__ W1t, const float* __restrict__ b1,
    const float* __restrict__ W2t, const float* __restrict__ b2,
    float* __restrict__ out, int N) {
    __shared__ unsigned int sedge[CAP];       // 20 KB; H2 overlays after pass 4
    __shared__ int scnt[NPB];
    __shared__ int soff[NPB];
    __shared__ __half2 aggL[NPB * 8];         // [node][ch-pair], 4 KB
    __half2* H2 = (__half2*)sedge;            // [kp][lane], 16 KB (union)

    int b = blockIdx.x, tid = threadIdx.x;
    if (tid < NPB) scnt[tid] = 0;
    __syncthreads();

    int sub = tid >> 1, l = tid & 1;          // 256 sub-runs, 2 lanes each
    int sc  = cnts[b * NBLK_A + sub];
    unsigned int base = (unsigned int)b * BKTSTRIDE + (unsigned int)sub * SUBCAP;

    // pass 1: per-node counts
    for (int j = l; j < sc; j += 2)
        atomicAdd(&scnt[binned[base + j] >> 17], 1);
    __syncthreads();

    // pass 2: exclusive scan over 128 (Hillis-Steele)
    if (tid < NPB) soff[tid] = scnt[tid];
    __syncthreads();
    for (int off = 1; off < NPB; off <<= 1) {
        int y = 0;
        if (tid < NPB && tid >= off) y = soff[tid - off];
        __syncthreads();
        if (tid < NPB) soff[tid] += y;
        __syncthreads();
    }
    if (tid < NPB) soff[tid] -= scnt[tid];
    __syncthreads();

    // pass 3: scatter into node-sorted sedge (L2-hot re-read)
    for (int j = l; j < sc; j += 2) {
        unsigned int p = binned[base + j];
        int pos = atomicAdd(&soff[p >> 17], 1);
        sedge[pos] = p & 0x1FFFFu;
    }
    __syncthreads();

    // pass 4: accumulate, 4 lanes/node, 8B gathers; result to aggL (LDS)
    {
        int nl = tid >> 2, q = tid & 3;
        int c  = scnt[nl];
        int s0 = soff[nl] - c;                // soff advanced to row end
        float a0 = 0.f, a1 = 0.f, a2 = 0.f, a3 = 0.f;
        #pragma unroll 4
        for (int k = 0; k < c; k++) {
            int col = (int)sedge[s0 + k];     // broadcast within quad
            uint2 raw = ((const uint2*)(xcon + (size_t)col * 16))[q];
            float2 f0 = __half22float2(*(const __half2*)&raw.x);
            float2 f1 = __half22float2(*(const __half2*)&raw.y);
            a0 += f0.x; a1 += f0.y; a2 += f1.x; a3 += f1.y;
        }
        float inv = 1.0f / (float)max(c, 1);
        aggL[nl * 8 + q * 2]     = __floats2half2_rn(a0 * inv, a1 * inv);
        aggL[nl * 8 + q * 2 + 1] = __floats2half2_rn(a2 * inv, a3 * inv);
    }
    __syncthreads();                          // aggL ready; sedge now dead

    // MLP: two 64-node tiles; 8 waves = 8 slices per tile
    int lane = tid & 63;
    int ws   = __builtin_amdgcn_readfirstlane(tid >> 6);   // 0..7
    #pragma unroll
    for (int t = 0; t < 2; t++) {
        int nlocal = t * 64 + lane;
        int n  = b * NPB + nlocal;
        int nc = min(n, N - 1);

        float comb[32];
        const float4* xr = (const float4*)(x + (size_t)nc * 32);
        #pragma unroll
        for (int c = 0; c < 4; c++) {
            float4 v = xr[c];
            comb[c*4+0] = v.x; comb[c*4+1] = v.y;
            comb[c*4+2] = v.z; comb[c*4+3] = v.w;
        }
        #pragma unroll
        for (int c = 0; c < 8; c++) {
            float2 f = __half22float2(aggL[nlocal * 8 + c]);
            comb[16 + 2*c]     = f.x;
            comb[16 + 2*c + 1] = f.y;
        }

        // phase A: 16 hidden units per wave, f16 pairs into H2
        #pragma unroll
        for (int i = 0; i < 16; i += 2) {
            int k0 = ws * 16 + i;                    // wave-uniform
            const float* w1a = W1t + k0 * 32;
            const float* w1b = w1a + 32;
            float ha = b1[k0], hb = b1[k0 + 1];
            #pragma unroll
            for (int c = 0; c < 32; c++) {
                ha = fmaf(comb[c], w1a[c], ha);
                hb = fmaf(comb[c], w1b[c], hb);
            }
            ha = fmaxf(ha, 0.f); hb = fmaxf(hb, 0.f);
            H2[(k0 >> 1) * 64 + lane] = __floats2half2_rn(ha, hb);
        }
        __syncthreads();

        // phase B: 4 outputs per wave
        int o0 = ws * 4;                             // wave-uniform
        const float* w20 = W2t + (o0 + 0) * 128;
        const float* w21 = W2t + (o0 + 1) * 128;
        const float* w22 = W2t + (o0 + 2) * 128;
        const float* w23 = W2t + (o0 + 3) * 128;
        float acc0 = b2[o0+0], acc1 = b2[o0+1], acc2 = b2[o0+2], acc3 = b2[o0+3];
        #pragma unroll 8
        for (int kp = 0; kp < 64; kp++) {
            float2 h = __half22float2(H2[kp * 64 + lane]);
            int k0 = 2 * kp;
            acc0 = fmaf(h.x, w20[k0], acc0); acc0 = fmaf(h.y, w20[k0+1], acc0);
            acc1 = fmaf(h.x, w21[k0], acc1); acc1 = fmaf(h.y, w21[k0+1], acc1);
            acc2 = fmaf(h.x, w22[k0], acc2); acc2 = fmaf(h.y, w22[k0+1], acc2);
            acc3 = fmaf(h.x, w23[k0], acc3); acc3 = fmaf(h.y, w23[k0+1], acc3);
        }
        if (n < N) {
            float* op = out + (size_t)n * 32 + o0;
            op[0] = acc0; op[1] = acc1; op[2] = acc2; op[3] = acc3;
        }
        __syncthreads();                             // H2 reused next tile
    }
}

extern "C" void kernel_launch(void* const* d_in, const int* in_sizes, int n_in,
                              void* d_out, int out_size, void* d_ws, size_t ws_size,
                              hipStream_t stream) {
    const float* x   = (const float*)d_in[0];
    const int*   idx = (const int*)d_in[1];
    const float* W1  = (const float*)d_in[2];
    const float* b1  = (const float*)d_in[3];
    const float* W2  = (const float*)d_in[4];
    const float* b2  = (const float*)d_in[5];
    float* out = (float*)d_out;

    const int E = in_sizes[1] / 2;     // 1,600,000
    const int total = 2 * E;           // 3,200,000
    const int chunk = (total + NBLK_A - 1) / NBLK_A;   // 12,500

    // ws layout (~55 MB of 256 MiB): xcon f16 | W1t | W2t | cnts | binned
    char* base = (char*)d_ws;
    __half*       xcon   = (__half*)(base + XCON_OFF);
    float*        W1t    = (float*)(base + W1T_OFF);
    float*        W2t    = (float*)(base + W2T_OFF);
    int*          cnts   = (int*)(base + CNTS_OFF);
    unsigned int* binned = (unsigned int*)(base + BINNED_OFF);

    int pack_blocks = (N_NODES * 8 + BTHR - 1) / BTHR;   // 782
    binfuse_kernel<<<NBLK_A + 1 + pack_blocks, BTHR, 0, stream>>>(
        idx, x, (__half2*)xcon, W1, W2, W1t, W2t,
        binned, cnts, chunk, total, E);
    aggmlp_kernel<<<NBKT, 512, 0, stream>>>(
        xcon, cnts, binned, x, W1t, b1, W2t, b2, out, N_NODES);
}

// Round 14
// 166.687 us; speedup vs baseline: 1.1006x; 1.1006x over previous
//
#include <hip/hip_runtime.h>
#include <hip/hip_bf16.h>
#include <hip/hip_fp16.h>

#define N_NODES  100000
#define N_RADIAL 16
#define N_CONICAL 16

#define NPB    256                                   // nodes per bucket (binfuse granularity)
#define NBKT   ((N_NODES + NPB - 1) / NPB)           // 391 buckets
#define NBLK_A 256                                   // binfuse scatter blocks
#define BTHR   512                                   // binfuse block threads
#define SUBCAP 96                                    // per-(block,bucket) sub-run cap (+11σ)
#define BKTSTRIDE (NBLK_A * SUBCAP)                  // 24576 slots per bucket
#define HNODES 128                                   // nodes per agg half
#define NSTRIDE 97                                   // sedge per-node stride (97%32=1 -> accumulate
                                                     // reads hit 16 distinct banks; 96 would be 16-way)

// ws byte offsets (R11-verified layout)
#define AGG_OFF    0u
#define XCON_OFF   3203072u
#define W1T_OFF    6406144u
#define W2T_OFF    6422528u
#define CNTS_OFF   6438912u
#define BINNED_OFF 6839296u

// ---------------------------------------------------------------------------
// A. Fused bin+prep (R11-verified 45-48us) + capacity clamp on the sub-run
//    cursor store (drops edges past cap instead of corrupting the neighbor
//    sub-run; never taken at +11σ, but guarantees no OOB store).
// ---------------------------------------------------------------------------
__global__ __launch_bounds__(BTHR) void binfuse_kernel(
    const int* __restrict__ idx, const float* __restrict__ x,
    __half2* __restrict__ xcon2,
    const float* __restrict__ W1, const float* __restrict__ W2,
    float* __restrict__ W1t, float* __restrict__ W2t,
    unsigned int* __restrict__ binned, int* __restrict__ cnts,
    int chunk, int total, int E) {
    int b = blockIdx.x, tid = threadIdx.x;
    if (b >= NBLK_A) {
        int pb = b - NBLK_A;
        if (pb == 0) {                       // weight transposes (4096 each)
            for (int i = tid; i < 4096; i += BTHR) {
                int c = i >> 7, k = i & 127;
                W1t[k * 32 + c] = W1[i];     // W1[c][k] -> W1t[k][c]
                int kk = i >> 5, o = i & 31;
                W2t[o * 128 + kk] = W2[i];   // W2[k][o] -> W2t[o][k]
            }
        } else {                             // xcon pack: one half2/thread
            int t = (pb - 1) * BTHR + tid;
            if (t < N_NODES * 8) {
                int n = t >> 3, p = t & 7;
                const float2* xp = (const float2*)x;
                float2 v = xp[n * 16 + 8 + p];
                xcon2[t] = __floats2half2_rn(v.x, v.y);
            }
        }
        return;
    }

    __shared__ int cur[NBKT];
    for (int i = tid; i < NBKT; i += BTHR)
        cur[i] = i * BKTSTRIDE + b * SUBCAP;       // absolute slot cursor
    __syncthreads();

    int lo = b * chunk;
    int hi = min(lo + chunk, total);
    for (int d = lo + tid; d < hi; d += BTHR) {
        int row = idx[d];
        int col = (d < E) ? idx[d + E] : idx[d - E];
        int bkt = row >> 8;
        int p = atomicAdd(&cur[bkt], 1);
        // clamp: stay inside this (block,bucket) sub-run
        if (p < bkt * BKTSTRIDE + b * SUBCAP + SUBCAP)
            binned[p] = ((unsigned int)(row & 255) << 17) | (unsigned int)col;
    }
    __syncthreads();

    for (int i = tid; i < NBKT; i += BTHR)
        cnts[i * NBLK_A + b] =
            min(cur[i] - (i * BKTSTRIDE + b * SUBCAP), SUBCAP);
}

// ---------------------------------------------------------------------------
// B. Bucket accumulate v4 — 1 LDS atomic per edge (replaces R11's counting
//    sort, 2 atomics/edge ~42us of LDS-atomic pipe). Fixed-capacity per-node
//    slots: cap 97 at mean degree 32 (P(>97)~1e-19), clamped so even an
//    impossible overflow cannot leave sedge. 128 nodes/half, two sequential
//    halves per 256-node bucket (predicated placement; sub-run region is
//    L2-resident so the second read is L2-hot). Counts from final cursors.
//    Accumulate: 4 lanes/node, 8B gathers from L2-resident xcon (R7-pattern).
// ---------------------------------------------------------------------------
__global__ __launch_bounds__(1024, 2) void agg_kernel(
    const __half* __restrict__ xcon, const int* __restrict__ cnts,
    const unsigned int* __restrict__ binned, __half* __restrict__ agg) {
    __shared__ unsigned int sedge[HNODES * NSTRIDE];   // 49664 B
    __shared__ int cur[HNODES];
    int b = blockIdx.x, tid = threadIdx.x;

    int sub = tid >> 2, l = tid & 3;          // 256 sub-runs, 4 lanes each
    int sc  = min(cnts[b * NBLK_A + sub], SUBCAP);
    unsigned int base = (unsigned int)b * BKTSTRIDE + (unsigned int)sub * SUBCAP;

    for (int h = 0; h < 2; h++) {
        if (tid < HNODES) cur[tid] = tid * NSTRIDE;
        __syncthreads();

        // placement: ONE atomic per edge; clamp keeps every store inside the
        // node's 97-slot region (never taken statistically)
        for (int j = l; j < sc; j += 4) {
            unsigned int p = binned[base + j];
            int rl = (int)(p >> 17);
            if ((rl >> 7) == h) {
                int nl = rl & 127;
                int pos = atomicAdd(&cur[nl], 1);
                if (pos < nl * NSTRIDE + NSTRIDE)
                    sedge[pos] = p & 0x1FFFFu;
            }
        }
        __syncthreads();

        // accumulate: 4 lanes/node over 128 nodes (threads 512+ idle)
        if (tid < 4 * HNODES) {
            int nl = tid >> 2, q = tid & 3;
            int c  = min(cur[nl] - nl * NSTRIDE, NSTRIDE);
            int s0 = nl * NSTRIDE;
            float a0 = 0.f, a1 = 0.f, a2 = 0.f, a3 = 0.f;
            #pragma unroll 4
            for (int k = 0; k < c; k++) {
                int col = (int)sedge[s0 + k];     // broadcast within quad
                uint2 raw = ((const uint2*)(xcon + (size_t)col * 16))[q];
                float2 f0 = __half22float2(*(const __half2*)&raw.x);
                float2 f1 = __half22float2(*(const __half2*)&raw.y);
                a0 += f0.x; a1 += f0.y; a2 += f1.x; a3 += f1.y;
            }
            int n = b * NPB + h * HNODES + nl;
            if (n < N_NODES) {
                float inv = 1.0f / (float)max(c, 1);
                __half2 h0 = __floats2half2_rn(a0 * inv, a1 * inv);
                __half2 h1 = __floats2half2_rn(a2 * inv, a3 * inv);
                uint2 st;
                st.x = *(unsigned int*)&h0;
                st.y = *(unsigned int*)&h1;
                *(uint2*)(agg + (size_t)n * 16 + q * 4) = st;  // 8B/lane
            }
        }
        __syncthreads();
    }
}

// ---------------------------------------------------------------------------
// C. MLP — EXACT R9/R11 kernel (verified ~20us): fused two-phase, 8 waves
//    per 64-node tile. Phase A: wave ws computes h[k=ws*16..+15] (k wave-
//    uniform -> W1t on the scalar pipe), h-pairs f16 in LDS H2[kp][node].
//    Phase B: wave ws computes outs o=ws*4..+3 from H2 + s_load'ed W2t.
// ---------------------------------------------------------------------------
__global__ __launch_bounds__(512, 4) void mlp_kernel(
    const float* __restrict__ x, const __half* __restrict__ agg,
    const float* __restrict__ W1t, const float* __restrict__ b1,
    const float* __restrict__ W2t, const float* __restrict__ b2,
    float* __restrict__ out, int N) {
    __shared__ __half2 H2[64 * 64];   // [kp][node], 16 KB
    int tid  = threadIdx.x;
    int lane = tid & 63;
    int ws   = __builtin_amdgcn_readfirstlane(tid >> 6);
    int n    = blockIdx.x * 64 + lane;
    int nc   = min(n, N - 1);

    float comb[32];
    const float4* xr = (const float4*)(x + (size_t)nc * 32);
    #pragma unroll
    for (int c = 0; c < 4; c++) {
        float4 v = xr[c];
        comb[c*4+0] = v.x; comb[c*4+1] = v.y;
        comb[c*4+2] = v.z; comb[c*4+3] = v.w;
    }
    const __half2* ar = (const __half2*)(agg + (size_t)nc * 16);
    #pragma unroll
    for (int c = 0; c < 8; c++) {
        float2 f = __half22float2(ar[c]);
        comb[16 + 2*c]     = f.x;
        comb[16 + 2*c + 1] = f.y;
    }

    #pragma unroll
    for (int i = 0; i < 16; i += 2) {
        int k0 = ws * 16 + i;
        const float* w1a = W1t + k0 * 32;
        const float* w1b = w1a + 32;
        float ha = b1[k0], hb = b1[k0 + 1];
        #pragma unroll
        for (int c = 0; c < 32; c++) {
            ha = fmaf(comb[c], w1a[c], ha);
            hb = fmaf(comb[c], w1b[c], hb);
        }
        ha = fmaxf(ha, 0.f); hb = fmaxf(hb, 0.f);
        H2[(k0 >> 1) * 64 + lane] = __floats2half2_rn(ha, hb);
    }
    __syncthreads();

    int o0 = ws * 4;
    const float* w20 = W2t + (o0 + 0) * 128;
    const float* w21 = W2t + (o0 + 1) * 128;
    const float* w22 = W2t + (o0 + 2) * 128;
    const float* w23 = W2t + (o0 + 3) * 128;
    float acc0 = b2[o0+0], acc1 = b2[o0+1], acc2 = b2[o0+2], acc3 = b2[o0+3];
    #pragma unroll 8
    for (int kp = 0; kp < 64; kp++) {
        float2 h = __half22float2(H2[kp * 64 + lane]);
        int k0 = 2 * kp;
        acc0 = fmaf(h.x, w20[k0], acc0); acc0 = fmaf(h.y, w20[k0+1], acc0);
        acc1 = fmaf(h.x, w21[k0], acc1); acc1 = fmaf(h.y, w21[k0+1], acc1);
        acc2 = fmaf(h.x, w22[k0], acc2); acc2 = fmaf(h.y, w22[k0+1], acc2);
        acc3 = fmaf(h.x, w23[k0], acc3); acc3 = fmaf(h.y, w23[k0+1], acc3);
    }
    if (n < N) {
        float* op = out + (size_t)n * 32 + o0;
        op[0] = acc0; op[1] = acc1; op[2] = acc2; op[3] = acc3;
    }
}

extern "C" void kernel_launch(void* const* d_in, const int* in_sizes, int n_in,
                              void* d_out, int out_size, void* d_ws, size_t ws_size,
                              hipStream_t stream) {
    const float* x   = (const float*)d_in[0];
    const int*   idx = (const int*)d_in[1];
    const float* W1  = (const float*)d_in[2];
    const float* b1  = (const float*)d_in[3];
    const float* W2  = (const float*)d_in[4];
    const float* b2  = (const float*)d_in[5];
    float* out = (float*)d_out;

    const int E = in_sizes[1] / 2;     // 1,600,000
    const int total = 2 * E;           // 3,200,000
    const int chunk = (total + NBLK_A - 1) / NBLK_A;   // 12,500

    // ws layout (R11-verified): agg f16 | xcon f16 | W1t | W2t | cnts | binned
    char* base = (char*)d_ws;
    __half*       agg    = (__half*)(base + AGG_OFF);
    __half*       xcon   = (__half*)(base + XCON_OFF);
    float*        W1t    = (float*)(base + W1T_OFF);
    float*        W2t    = (float*)(base + W2T_OFF);
    int*          cnts   = (int*)(base + CNTS_OFF);
    unsigned int* binned = (unsigned int*)(base + BINNED_OFF);

    int pack_blocks = (N_NODES * 8 + BTHR - 1) / BTHR;   // 1563
    binfuse_kernel<<<NBLK_A + 1 + pack_blocks, BTHR, 0, stream>>>(
        idx, x, (__half2*)xcon, W1, W2, W1t, W2t,
        binned, cnts, chunk, total, E);
    agg_kernel<<<NBKT, 1024, 0, stream>>>(xcon, cnts, binned, agg);
    mlp_kernel<<<(N_NODES + 63) / 64, 512, 0, stream>>>(
        x, agg, W1t, b1, W2t, b2, out, N_NODES);
}